// Round 1
// baseline (209.842 us; speedup 1.0000x reference)
//
#include <hip/hip_runtime.h>

#define NPTS     65536
#define BATCHES  16
#define CHANNELS 256
#define LOUT     8192
#define TJ       128       // j-tile per block
#define MAX_ROWS 72        // LDS row budget (72*257*4 = 74 KiB -> 2 blocks/CU)
#define STRIDE   257       // 256+1: odd stride -> conflict-free column gathers

// ---------------- kernel 1: per-batch offsets & counts --------------------
// batch[] is sorted ascending with values in [0, BATCHES). boundary[b] =
// lower_bound(batch, b); offsets[b] = boundary[b]; counts[b] = boundary[b+1]-boundary[b].
__global__ void k_offsets(const int* __restrict__ batch, int* __restrict__ ws) {
    const int t = threadIdx.x;
    __shared__ int bnd[BATCHES + 1];
    if (t <= BATCHES) {
        int lo = 0;
        if (t == BATCHES) {
            lo = NPTS;
        } else {
            int hi = NPTS;
            while (lo < hi) {
                int mid = (lo + hi) >> 1;
                if (batch[mid] < t) lo = mid + 1; else hi = mid;
            }
        }
        bnd[t] = lo;
    }
    __syncthreads();
    if (t < BATCHES) {
        ws[t]           = bnd[t];               // offsets
        ws[BATCHES + t] = bnd[t + 1] - bnd[t];  // counts
    }
}

// ---------------- kernel 2: main upsample/transpose -----------------------
// grid: 16 batches * 64 j-tiles = 1024 blocks of 256 threads (4 waves).
// Stage contiguous input rows [s0..s1] into LDS (coalesced float4 reads),
// then each wave emits one channel row: lanes hold j-pairs, ds_read_b32 x2
// from padded LDS, one coalesced 8B store. Points (3 rows) done by waves 0-2.
__global__ __launch_bounds__(256, 2) void k_main(
    const float* __restrict__ px,   // [N,3]
    const float* __restrict__ pf,   // [N,C]
    const int*   __restrict__ ws,   // offsets[16], counts[16]
    float*       __restrict__ out)  // [B*3*L] then [B*C*L]
{
    __shared__ float tile[MAX_ROWS * STRIDE];
    const int t    = threadIdx.x;
    const int lane = t & 63;
    const int wv   = t >> 6;
    const int b    = blockIdx.x >> 6;          // 64 tiles per batch
    const int j0   = (blockIdx.x & 63) * TJ;
    const int offs = ws[b];
    const int cnt  = ws[BATCHES + b];

    // src row for output index j (clamped for the degenerate empty-batch case)
    auto srow = [&](int j) -> int {
        int s = offs + ((j * cnt) >> 13);      // j*cnt < 2^30, L = 8192 = 2^13
        return s < (NPTS - 1) ? s : (NPTS - 1);
    };

    const int s0 = srow(j0);
    const int s1 = srow(j0 + TJ - 1);
    const int R  = s1 - s0 + 1;

    // per-lane j-pair source rows (hoisted out of the channel loop)
    const int j  = j0 + lane * 2;
    const int ga = srow(j);
    const int gb = srow(j + 1);

    float* outf = out + (size_t)BATCHES * 3 * LOUT;   // feature section base

    if (R <= MAX_ROWS) {
        // ---- stage rows [s0, s1] into LDS, coalesced float4 ----
        const float4* in4 = (const float4*)(pf + (size_t)s0 * CHANNELS);
        const int n4 = R * (CHANNELS / 4);
        for (int e = t; e < n4; e += 256) {
            const int row = e >> 6;            // CHANNELS/4 = 64 float4 per row
            const int c4  = e & 63;
            const float4 v = in4[row * 64 + c4];
            float* dst = &tile[row * STRIDE + c4 * 4];
            dst[0] = v.x; dst[1] = v.y; dst[2] = v.z; dst[3] = v.w;
        }
        __syncthreads();

        const int la = (ga - s0) * STRIDE;
        const int lb = (gb - s0) * STRIDE;
        float* op = outf + ((size_t)b * CHANNELS) * LOUT + j;
        #pragma unroll 4
        for (int c = wv; c < CHANNELS; c += 4) {
            float2 v;
            v.x = tile[la + c];
            v.y = tile[lb + c];
            *(float2*)(op + (size_t)c * LOUT) = v;
        }
    } else {
        // ---- fallback (severely skewed batch): direct global gather ----
        const float* ra = pf + (size_t)ga * CHANNELS;
        const float* rb = pf + (size_t)gb * CHANNELS;
        float* op = outf + ((size_t)b * CHANNELS) * LOUT + j;
        for (int c = wv; c < CHANNELS; c += 4) {
            float2 v;
            v.x = ra[c];
            v.y = rb[c];
            *(float2*)(op + (size_t)c * LOUT) = v;
        }
    }

    // ---- out_point: waves 0..2 each handle one coordinate d ----
    if (wv < 3) {
        const int d = wv;
        float2 v;
        v.x = px[ga * 3 + d];
        v.y = px[gb * 3 + d];
        *(float2*)(out + ((size_t)(b * 3 + d)) * LOUT + j) = v;
    }
}

extern "C" void kernel_launch(void* const* d_in, const int* in_sizes, int n_in,
                              void* d_out, int out_size, void* d_ws, size_t ws_size,
                              hipStream_t stream) {
    const float* px    = (const float*)d_in[0];   // points_x [N,3]
    const float* pf    = (const float*)d_in[1];   // point_features [N,C]
    const int*   batch = (const int*)d_in[2];     // batch ids [N], sorted
    float* out = (float*)d_out;
    int*   wsI = (int*)d_ws;

    k_offsets<<<1, 32, 0, stream>>>(batch, wsI);
    k_main<<<BATCHES * (LOUT / TJ), 256, 0, stream>>>(px, pf, wsI, out);
}

// Round 2
// 200.505 us; speedup vs baseline: 1.0466x; 1.0466x over previous
//
#include <hip/hip_runtime.h>

#define NPTS     65536
#define BATCHES  16
#define CHANNELS 256
#define LOUT     8192
#define TJ       64        // j-tile per block
#define NTILES   (LOUT / TJ)            // 128 tiles per batch
#define MAX_ROWS 38        // 38*257*4 = 39 KiB LDS -> 4 blocks/CU
#define STRIDE   257       // 256+1: gather bank = (row+c) mod 32 -> conflict-free

// Single kernel: per-block binary search for its batch's [offset,count),
// stage the needed contiguous input rows into padded LDS (coalesced float4),
// then transpose-gather: each wave owns a channel residue, lanes own j.
__global__ __launch_bounds__(256, 4) void k_main(
    const float* __restrict__ px,    // [N,3]
    const float* __restrict__ pf,    // [N,C]
    const int*   __restrict__ batch, // [N], sorted batch ids
    float*       __restrict__ out)   // [B*3*L] then [B*C*L]
{
    __shared__ float tile[MAX_ROWS * STRIDE];
    __shared__ int   sb[2];

    const int t    = threadIdx.x;
    const int lane = t & 63;
    const int wv   = t >> 6;
    const int b    = blockIdx.x >> 7;          // NTILES = 128
    const int j0   = (blockIdx.x & (NTILES - 1)) * TJ;

    // threads 0,1: lower_bound(batch, b + t)  (L2-hot after first blocks)
    if (t < 2) {
        const int target = b + t;
        int lo = 0;
        if (target >= BATCHES) {
            lo = NPTS;
        } else {
            int hi = NPTS;
            while (lo < hi) {
                const int mid = (lo + hi) >> 1;
                if (batch[mid] < target) lo = mid + 1; else hi = mid;
            }
        }
        sb[t] = lo;
    }
    __syncthreads();
    const int offs = sb[0];
    const int cnt  = sb[1] - sb[0];

    // output index j -> global source row (JAX clamps OOB gathers)
    auto srow = [&](int j) -> int {
        const int s = offs + ((j * cnt) >> 13);   // L = 8192 = 2^13
        return s < (NPTS - 1) ? s : (NPTS - 1);
    };

    const int s0 = srow(j0);
    const int s1 = srow(j0 + TJ - 1);
    const int R  = s1 - s0 + 1;

    const int j  = j0 + lane;          // one output column per lane
    const int ga = srow(j);

    float* outf = out + (size_t)BATCHES * 3 * LOUT;   // feature section

    if (R <= MAX_ROWS) {
        // ---- stage rows [s0, s1] into LDS, coalesced float4 ----
        const float4* in4 = (const float4*)(pf + (size_t)s0 * CHANNELS);
        const int n4 = R * (CHANNELS / 4);
        for (int e = t; e < n4; e += 256) {
            const int row = e >> 6;               // 64 float4 per row
            const int c4  = e & 63;
            const float4 v = in4[row * 64 + c4];
            float* dst = &tile[row * STRIDE + c4 * 4];
            dst[0] = v.x; dst[1] = v.y; dst[2] = v.z; dst[3] = v.w;
        }
        __syncthreads();

        const int la = (ga - s0) * STRIDE;
        float* op = outf + ((size_t)b * CHANNELS) * LOUT + j;
        #pragma unroll 8
        for (int c = wv; c < CHANNELS; c += 4) {
            __builtin_nontemporal_store(tile[la + c], op + (size_t)c * LOUT);
        }
    } else {
        // ---- fallback (pathologically skewed batch): direct gather ----
        const float* ra = pf + (size_t)ga * CHANNELS;
        float* op = outf + ((size_t)b * CHANNELS) * LOUT + j;
        for (int c = wv; c < CHANNELS; c += 4) {
            __builtin_nontemporal_store(ra[c], op + (size_t)c * LOUT);
        }
    }

    // ---- out_point: waves 0..2 handle coordinate d = wv ----
    if (wv < 3) {
        __builtin_nontemporal_store(px[ga * 3 + wv],
                                    out + ((size_t)(b * 3 + wv)) * LOUT + j);
    }
}

extern "C" void kernel_launch(void* const* d_in, const int* in_sizes, int n_in,
                              void* d_out, int out_size, void* d_ws, size_t ws_size,
                              hipStream_t stream) {
    const float* px    = (const float*)d_in[0];   // points_x [N,3]
    const float* pf    = (const float*)d_in[1];   // point_features [N,C]
    const int*   batch = (const int*)d_in[2];     // batch ids [N], sorted
    float* out = (float*)d_out;

    k_main<<<BATCHES * NTILES, 256, 0, stream>>>(px, pf, batch, out);
}

// Round 4
// 198.603 us; speedup vs baseline: 1.0566x; 1.0096x over previous
//
#include <hip/hip_runtime.h>

#define NPTS     65536
#define BATCHES  16
#define CHANNELS 256
#define LOUT     8192
#define TJ       256                  // j-extent per block -> 1KB write runs
#define CGRP     64                   // channels per block
#define NTILES   (LOUT / TJ)          // 32 j-tiles
#define NCG      (CHANNELS / CGRP)    // 4 channel groups
#define MAX_ROWS 152                  // 152*65*4 = 39.5 KB LDS -> 4 blocks/CU
#define STRIDE   (CGRP + 1)           // 65: gather bank = (row+c) mod 32, 2-way max

typedef float f32x2 __attribute__((ext_vector_type(2)));  // nt-store-compatible

// Block = (batch b, channel-group cg, j-tile). Binary-search the batch's
// [offset,count), stage rows [s0..s1] x 64 channels into padded LDS
// (coalesced float4), then transpose-gather: waves own channel residues,
// lanes own j-pairs -> 512B contiguous nt-stores into 1KB runs per channel.
__global__ __launch_bounds__(256, 4) void k_main(
    const float* __restrict__ px,    // [N,3]
    const float* __restrict__ pf,    // [N,C]
    const int*   __restrict__ batch, // [N], sorted batch ids
    float*       __restrict__ out)   // [B*3*L] then [B*C*L]
{
    __shared__ float tile[MAX_ROWS * STRIDE];
    __shared__ int   sb[2];

    const int t    = threadIdx.x;
    const int lane = t & 63;
    const int wv   = t >> 6;
    const int jt   = blockIdx.x & (NTILES - 1);
    const int cg   = (blockIdx.x >> 5) & (NCG - 1);
    const int b    = blockIdx.x >> 7;
    const int j0   = jt * TJ;

    // threads 0,1: lower_bound(batch, b + t)   (L2-hot after first blocks)
    if (t < 2) {
        const int target = b + t;
        int lo = 0;
        if (target >= BATCHES) {
            lo = NPTS;
        } else {
            int hi = NPTS;
            while (lo < hi) {
                const int mid = (lo + hi) >> 1;
                if (batch[mid] < target) lo = mid + 1; else hi = mid;
            }
        }
        sb[t] = lo;
    }
    __syncthreads();
    const int offs = sb[0];
    const int cnt  = sb[1] - sb[0];

    // output index j -> global source row (clamped like JAX OOB gather)
    auto srow = [&](int j) -> int {
        const int s = offs + ((j * cnt) >> 13);   // L = 8192 = 2^13
        return s < (NPTS - 1) ? s : (NPTS - 1);
    };

    const int s0 = srow(j0);
    const int s1 = srow(j0 + TJ - 1);
    const int R  = s1 - s0 + 1;

    // per-lane j-pair source rows, two passes k = 0,1 (128 j per pass)
    int gA[2], gB[2];
    #pragma unroll
    for (int k = 0; k < 2; ++k) {
        const int j = j0 + 2 * lane + 128 * k;
        gA[k] = srow(j);
        gB[k] = srow(j + 1);
    }

    float* outf = out + (size_t)BATCHES * 3 * LOUT;   // feature section
    float* opBase = outf + ((size_t)(b * CHANNELS + cg * CGRP)) * LOUT + j0 + 2 * lane;

    if (R <= MAX_ROWS) {
        // ---- stage rows [s0,s1] x this channel group into LDS ----
        const float4* in4 = (const float4*)(pf + (size_t)s0 * CHANNELS + cg * CGRP);
        const int n4 = R * (CGRP / 4);            // 16 float4 per row
        for (int e = t; e < n4; e += 256) {
            const int row = e >> 4;
            const int c4  = e & 15;
            const float4 v = in4[row * (CHANNELS / 4) + c4];
            float* dst = &tile[row * STRIDE + c4 * 4];
            dst[0] = v.x; dst[1] = v.y; dst[2] = v.z; dst[3] = v.w;
        }
        __syncthreads();

        const int laA0 = (gA[0] - s0) * STRIDE, laB0 = (gB[0] - s0) * STRIDE;
        const int laA1 = (gA[1] - s0) * STRIDE, laB1 = (gB[1] - s0) * STRIDE;
        #pragma unroll 4
        for (int c = wv; c < CGRP; c += 4) {
            float* op = opBase + (size_t)c * LOUT;
            f32x2 v0, v1;
            v0.x = tile[laA0 + c]; v0.y = tile[laB0 + c];
            v1.x = tile[laA1 + c]; v1.y = tile[laB1 + c];
            __builtin_nontemporal_store(v0, (f32x2*)op);
            __builtin_nontemporal_store(v1, (f32x2*)(op + 128));
        }
    } else {
        // ---- fallback (pathologically skewed batch): direct gather ----
        for (int c = wv; c < CGRP; c += 4) {
            float* op = opBase + (size_t)c * LOUT;
            const int cc = cg * CGRP + c;
            f32x2 v0, v1;
            v0.x = pf[(size_t)gA[0] * CHANNELS + cc];
            v0.y = pf[(size_t)gB[0] * CHANNELS + cc];
            v1.x = pf[(size_t)gA[1] * CHANNELS + cc];
            v1.y = pf[(size_t)gB[1] * CHANNELS + cc];
            __builtin_nontemporal_store(v0, (f32x2*)op);
            __builtin_nontemporal_store(v1, (f32x2*)(op + 128));
        }
    }

    // ---- out_point: only cg==0 blocks, waves 0..2 handle coord d = wv ----
    if (cg == 0 && wv < 3) {
        #pragma unroll
        for (int k = 0; k < 2; ++k) {
            f32x2 v;
            v.x = px[gA[k] * 3 + wv];
            v.y = px[gB[k] * 3 + wv];
            __builtin_nontemporal_store(
                v, (f32x2*)(out + ((size_t)(b * 3 + wv)) * LOUT + j0 + 2 * lane + 128 * k));
        }
    }
}

extern "C" void kernel_launch(void* const* d_in, const int* in_sizes, int n_in,
                              void* d_out, int out_size, void* d_ws, size_t ws_size,
                              hipStream_t stream) {
    const float* px    = (const float*)d_in[0];   // points_x [N,3]
    const float* pf    = (const float*)d_in[1];   // point_features [N,C]
    const int*   batch = (const int*)d_in[2];     // batch ids [N], sorted
    float* out = (float*)d_out;

    k_main<<<BATCHES * NCG * NTILES, 256, 0, stream>>>(px, pf, batch, out);
}